// Round 8
// baseline (68.966 us; speedup 1.0000x reference)
//
#include <hip/hip_runtime.h>

#define CLS 8
#define BATCH 8
#define NSLICE 8
#define LOG2E 1.442695040888963f
#define LN2   0.693147180559945f

#define F4C(v, e) ((e) == 0 ? (v).x : (e) == 1 ? (v).y : (e) == 2 ? (v).z : (v).w)

struct WS {
    float    S[NSLICE][BATCH][64];   // S[b][c*8+k] = sum_{p: t=k} pred[c][p]
    float    n[NSLICE][BATCH][CLS];  // class pixel counts
    float    lse[NSLICE];            // sum of log2(sum_c exp2(p_c*log2e))
    unsigned cnt;                    // K2 completion ticket
};

__device__ __forceinline__ float wave_reduce(float v) {
#pragma unroll
    for (int off = 32; off > 0; off >>= 1) v += __shfl_xor(v, off);
    return v;
}

// ---------------- K1: J-term. One block = one contiguous 32KB span of one
// (batch, channel) row. Single linear stream; acc is only 8 registers. ------
__global__ __launch_bounds__(256, 6) void jce_j(
    const float* __restrict__ pred, const int* __restrict__ tgt,
    WS* ws, int N)
{
    const int tid   = threadIdx.x;
    const int row   = blockIdx.x >> 5;        // b*8 + c
    const int chunk = blockIdx.x & 31;        // 32 chunks x 8192 px = 262144
    const int b = row >> 3, c = row & 7;
    const float* ps = pred + (size_t)row * N + chunk * 8192;
    const int*   ts = tgt  + (size_t)b   * N + chunk * 8192;

    float acc[CLS];
#pragma unroll
    for (int k = 0; k < CLS; ++k) acc[k] = 0.f;

    float4 pA, pB;
    int4   tA, tB;

#define LD(P, T, it) do {                                                   \
        (P) = *reinterpret_cast<const float4*>(ps + (it) * 1024 + tid * 4); \
        (T) = *reinterpret_cast<const int4*>(ts + (it) * 1024 + tid * 4);   \
    } while (0)

#define CK(P, T) do {                                                       \
        _Pragma("unroll")                                                   \
        for (int _e = 0; _e < 4; ++_e) {                                    \
            const float _pc = F4C((P), _e);                                 \
            const int   _tv = F4C((T), _e);                                 \
            _Pragma("unroll")                                               \
            for (int _k = 0; _k < CLS; ++_k)                                \
                acc[_k] += (_tv == _k) ? _pc : 0.f;                         \
        }                                                                   \
    } while (0)

    LD(pA, tA, 0);
    LD(pB, tB, 1);
#pragma unroll
    for (int it = 0; it < 8; it += 2) {
        CK(pA, tA);
        if (it + 2 < 8) LD(pA, tA, it + 2);
        CK(pB, tB);
        if (it + 3 < 8) LD(pB, tB, it + 3);
    }
#undef LD
#undef CK

    // reduce acc[8] across 64 lanes; lanes 0-7 end holding class totals
    const int lane = tid & 63;
    const int wv   = tid >> 6;
    float keep = 0.f;
#pragma unroll
    for (int k = 0; k < CLS; ++k) {
        const float r = wave_reduce(acc[k]);
        if (lane == k) keep = r;
    }
    __shared__ float red[4][CLS];
    if (lane < CLS) red[wv][lane] = keep;
    __syncthreads();
    if (tid < CLS) {
        const float v = red[0][tid] + red[1][tid] + red[2][tid] + red[3][tid];
        atomicAdd(&ws->S[chunk & (NSLICE - 1)][b][c * 8 + tid], v);
    }
}

// ---------------- K2: CE (lse) + class counts, channel-major per block so a
// single contiguous 8KB stream is live at a time; s[8] per-pixel partials in
// registers. Fused last-block epilogue (reads K1's S, stream-ordered). ------
__global__ __launch_bounds__(256, 6) void jce_ce(
    const float* __restrict__ pred, const int* __restrict__ tgt,
    const float* __restrict__ w, float* __restrict__ out,
    WS* ws, int N)
{
    const int tid  = threadIdx.x;
    const int b    = blockIdx.x >> 7;         // 128 blocks per batch
    const int span = (blockIdx.x & 127) * 2048;
    const int lane = tid & 63;
    const int wv   = tid >> 6;
    const float* pb = pred + (size_t)b * CLS * N + span;
    const int*   tb = tgt  + (size_t)b * N + span;

    float s[8];
#pragma unroll
    for (int j = 0; j < 8; ++j) s[j] = 0.f;

    float4 a0, a1, b0, b1;
#define LDC(X0, X1, c) do {                                                        \
        (X0) = *reinterpret_cast<const float4*>(pb + (size_t)(c) * N + tid * 4);   \
        (X1) = *reinterpret_cast<const float4*>(pb + (size_t)(c) * N + 1024 + tid * 4); \
    } while (0)
#define ACCC(X0, X1) do {                                                          \
        s[0] += exp2f((X0).x * LOG2E); s[1] += exp2f((X0).y * LOG2E);              \
        s[2] += exp2f((X0).z * LOG2E); s[3] += exp2f((X0).w * LOG2E);              \
        s[4] += exp2f((X1).x * LOG2E); s[5] += exp2f((X1).y * LOG2E);              \
        s[6] += exp2f((X1).z * LOG2E); s[7] += exp2f((X1).w * LOG2E);              \
    } while (0)

    LDC(a0, a1, 0);
#pragma unroll
    for (int c = 0; c < 8; c += 2) {
        if (c + 1 < 8) LDC(b0, b1, c + 1);
        ACCC(a0, a1);
        if (c + 2 < 8) LDC(a0, a1, c + 2);
        ACCC(b0, b1);
    }
#undef LDC
#undef ACCC

    float lsum = 0.f;
#pragma unroll
    for (int j = 0; j < 8; ++j) lsum += log2f(s[j]);
    const float lw = wave_reduce(lsum);

    // class counts for this block's 2048 pixels
    const int4 t0 = *reinterpret_cast<const int4*>(tb + tid * 4);
    const int4 t1 = *reinterpret_cast<const int4*>(tb + 1024 + tid * 4);
    float nkeep = 0.f;
#pragma unroll
    for (int k = 0; k < CLS; ++k) {
        float ck = (t0.x == k) + (t0.y == k) + (t0.z == k) + (t0.w == k)
                 + (t1.x == k) + (t1.y == k) + (t1.z == k) + (t1.w == k);
        ck = wave_reduce(ck);
        if (lane == k) nkeep = ck;
    }

    __shared__ float redl[4];
    __shared__ float redn[4][CLS];
    if (lane == 0) redl[wv] = lw;
    if (lane < CLS) redn[wv][lane] = nkeep;
    __syncthreads();

    const int sl = blockIdx.x & (NSLICE - 1);
    if (tid < CLS) {
        const float v = redn[0][tid] + redn[1][tid] + redn[2][tid] + redn[3][tid];
        atomicAdd(&ws->n[sl][b][tid], v);
    } else if (tid == CLS) {
        atomicAdd(&ws->lse[sl], (redl[0] + redl[1] + redl[2] + redl[3]) * LN2);
    }

    // ---- last-block-done epilogue ----
    __syncthreads();
    __shared__ int lastFlag;
    if (tid == 0) {
        __threadfence();
        const unsigned t = atomicAdd(&ws->cnt, 1u);
        lastFlag = (t == gridDim.x - 1) ? 1 : 0;
    }
    __syncthreads();
    if (!lastFlag) return;
    __threadfence();

    __shared__ float epi[576];             // eS[8][64] + eN[8][8]
    __shared__ float eLse, eCe;
    for (int j = tid; j < 577; j += 256) {
        float acc = 0.f;
        if (j < 512) {
            const int bb = j >> 6, ee = j & 63;
#pragma unroll
            for (int s8 = 0; s8 < NSLICE; ++s8) acc += atomicAdd(&ws->S[s8][bb][ee], 0.f);
            epi[j] = acc;
        } else if (j < 576) {
            const int q = j - 512, bb = q >> 3, k = q & 7;
#pragma unroll
            for (int s8 = 0; s8 < NSLICE; ++s8) acc += atomicAdd(&ws->n[s8][bb][k], 0.f);
            epi[j] = acc;
        } else {
#pragma unroll
            for (int s8 = 0; s8 < NSLICE; ++s8) acc += atomicAdd(&ws->lse[s8], 0.f);
            eLse = acc;
        }
    }
    __syncthreads();

    // ce = (sum lse - sum_b trace(S_b)) / (B*N)
    if (tid < 64) {
        const int bb = tid >> 3, kk = tid & 7;
        float tv = epi[bb * 64 + kk * 9];
        tv = wave_reduce(tv);
        if (tid == 0) eCe = (eLse - tv) / ((float)BATCH * (float)N);
    }
    __syncthreads();

    // j[b] = -sum_{i!=k} w[i,k]*log(0.5 + 0.5*(A[i,i]-A[i,k])); out = j + ce
    const int i = lane >> 3, k = lane & 7;
#pragma unroll
    for (int r = 0; r < 2; ++r) {
        const int bb = wv * 2 + r;             // 4 waves x 2 batches
        const float A    = epi[bb * 64 + lane] / epi[512 + bb * 8 + k];
        const float diag = epi[bb * 64 + i * 9] / epi[512 + bb * 8 + i];
        float term = 0.f;
        if (i != k)
            term = w[lane] * (log2f(0.5f + 0.5f * (diag - A)) * LN2);
        term = wave_reduce(term);
        if (lane == 0) out[bb] = -term + eCe;
    }
}

extern "C" void kernel_launch(void* const* d_in, const int* in_sizes, int n_in,
                              void* d_out, int out_size, void* d_ws, size_t ws_size,
                              hipStream_t stream) {
    const float* pred = (const float*)d_in[0];
    const int*   tgt  = (const int*)d_in[1];
    const float* w    = (const float*)d_in[2];
    float* out = (float*)d_out;

    const int N = in_sizes[1] / BATCH;        // H*W = 262144
    WS* ws = (WS*)d_ws;

    hipMemsetAsync(ws, 0, sizeof(WS), stream);
    jce_j <<<dim3(BATCH * CLS * 32), dim3(256), 0, stream>>>(pred, tgt, ws, N);
    jce_ce<<<dim3(BATCH * 128),      dim3(256), 0, stream>>>(pred, tgt, w, out, ws, N);
}

// Round 9
// 49.006 us; speedup vs baseline: 1.4073x; 1.4073x over previous
//
#include <hip/hip_runtime.h>

#define CLS 8
#define BATCH 8
#define THREADS 1024
#define SPAN 8192                    // px per block -> each channel-visit is a 32 KB contiguous run
#define NSLICE 8
#define LOG2E 1.442695040888963f
#define LN2   0.693147180559945f

#define F4C(v, e) ((e) == 0 ? (v).x : (e) == 1 ? (v).y : (e) == 2 ? (v).z : (v).w)

struct WS {
    float    S[NSLICE][BATCH][64];   // S[b][c*8+k] = sum_{p: t=k} pred[c][p]
    float    n[NSLICE][BATCH][CLS];  // class pixel counts
    float    lse[NSLICE];            // natural-log lse sum
    unsigned cnt;                    // completion ticket
};

__device__ __forceinline__ float wave_reduce(float v) {
#pragma unroll
    for (int off = 32; off > 0; off >>= 1) v += __shfl_xor(v, off);
    return v;
}

__global__ __launch_bounds__(THREADS, 4) void jce_fused(
    const float* __restrict__ pred, const int* __restrict__ tgt,
    const float* __restrict__ w, float* __restrict__ out,
    WS* ws, int N)
{
    const int tid   = threadIdx.x;
    const int b     = blockIdx.x >> 5;          // 32 blocks per batch
    const int chunk = blockIdx.x & 31;
    const int span  = chunk * SPAN;
    const int lane  = tid & 63;
    const int wv    = tid >> 6;                 // 16 waves
    const float* pb = pred + (size_t)b * CLS * N + span;
    const int*   tb = tgt  + (size_t)b * N + span;

    // targets for this thread's 8 pixels (two float4-slots), held whole kernel
    const int4 t0 = *reinterpret_cast<const int4*>(tb + tid * 4);
    const int4 t1 = *reinterpret_cast<const int4*>(tb + 4096 + tid * 4);

    float acc[64];                              // acc[c*8+k] = sum_{p: t=k} pred[c][p]
#pragma unroll
    for (int j = 0; j < 64; ++j) acc[j] = 0.f;
    float s[8];                                 // per-pixel running sum of exp2(p*log2e)
#pragma unroll
    for (int j = 0; j < 8; ++j) s[j] = 0.f;

    float4 a0, a1, c0, c1;

    // one channel-visit = one contiguous 32 KB run (K1-proven granularity)
#define LDC(X0, X1, c) do {                                                          \
        (X0) = *reinterpret_cast<const float4*>(pb + (size_t)(c) * N + tid * 4);     \
        (X1) = *reinterpret_cast<const float4*>(pb + (size_t)(c) * N + 4096 + tid * 4); \
    } while (0)

#define ACCC(X0, X1, c) do {                                                         \
        _Pragma("unroll")                                                            \
        for (int _e = 0; _e < 4; ++_e) {                                             \
            const float _p0 = F4C((X0), _e);                                         \
            const int   _v0 = F4C(t0, _e);                                           \
            s[_e] += exp2f(_p0 * LOG2E);                                             \
            _Pragma("unroll")                                                        \
            for (int _k = 0; _k < CLS; ++_k)                                         \
                acc[(c) * 8 + _k] += (_v0 == _k) ? _p0 : 0.f;                        \
            const float _p1 = F4C((X1), _e);                                         \
            const int   _v1 = F4C(t1, _e);                                           \
            s[4 + _e] += exp2f(_p1 * LOG2E);                                         \
            _Pragma("unroll")                                                        \
            for (int _k = 0; _k < CLS; ++_k)                                         \
                acc[(c) * 8 + _k] += (_v1 == _k) ? _p1 : 0.f;                        \
        }                                                                            \
    } while (0)

    LDC(a0, a1, 0);
    LDC(c0, c1, 1);
    ACCC(a0, a1, 0); LDC(a0, a1, 2);
    ACCC(c0, c1, 1); LDC(c0, c1, 3);
    ACCC(a0, a1, 2); LDC(a0, a1, 4);
    ACCC(c0, c1, 3); LDC(c0, c1, 5);
    ACCC(a0, a1, 4); LDC(a0, a1, 6);
    ACCC(c0, c1, 5); LDC(c0, c1, 7);
    ACCC(a0, a1, 6);
    ACCC(c0, c1, 7);
#undef LDC
#undef ACCC

    // CE partial: sum over this thread's 8 pixels of log2(sum_c exp2)
    float lsum = 0.f;
#pragma unroll
    for (int j = 0; j < 8; ++j) lsum += log2f(s[j]);

    // class counts via ballot (wave-uniform results)
    int cntk[CLS];
#pragma unroll
    for (int k = 0; k < CLS; ++k) {
        int c8 = 0;
        c8 += __popcll(__ballot(t0.x == k)); c8 += __popcll(__ballot(t0.y == k));
        c8 += __popcll(__ballot(t0.z == k)); c8 += __popcll(__ballot(t0.w == k));
        c8 += __popcll(__ballot(t1.x == k)); c8 += __popcll(__ballot(t1.y == k));
        c8 += __popcll(__ballot(t1.z == k)); c8 += __popcll(__ballot(t1.w == k));
        cntk[k] = c8;
    }

    // split-vector butterfly: lane l ends holding wave-total of entry bitrev6(l)
#pragma unroll
    for (int s6 = 0; s6 < 6; ++s6) {
        const int d = 1 << s6;
        const int half = 32 >> s6;
        const bool hi = (lane & d) != 0;
#pragma unroll
        for (int j = 0; j < half; ++j) {
            const float keep = hi ? acc[j + half] : acc[j];
            const float send = hi ? acc[j] : acc[j + half];
            acc[j] = keep + __shfl_xor(send, d);
        }
    }
    const int e6 = ((lane & 1) << 5) | ((lane & 2) << 3) | ((lane & 4) << 1) |
                   ((lane & 8) >> 1) | ((lane & 16) >> 3) | ((lane & 32) >> 5);

    __shared__ float redS[16][64];
    __shared__ float redl[16];
    __shared__ int   redc[16][CLS];

    redS[wv][e6] = acc[0];
    const float lw = wave_reduce(lsum);
    if (lane == 0) {
        redl[wv] = lw;
#pragma unroll
        for (int k = 0; k < CLS; ++k) redc[wv][k] = cntk[k];
    }
    __syncthreads();

    const int sl = blockIdx.x & (NSLICE - 1);
    if (tid < 64) {
        float v = 0.f;
#pragma unroll
        for (int q = 0; q < 16; ++q) v += redS[q][tid];
        atomicAdd(&ws->S[sl][b][tid], v);
    } else if (tid < 64 + CLS) {
        const int k = tid - 64;
        int v = 0;
#pragma unroll
        for (int q = 0; q < 16; ++q) v += redc[q][k];
        atomicAdd(&ws->n[sl][b][k], (float)v);
    } else if (tid == 64 + CLS) {
        float v = 0.f;
#pragma unroll
        for (int q = 0; q < 16; ++q) v += redl[q];
        atomicAdd(&ws->lse[sl], v * LN2);
    }

    // ---- last-block-done epilogue ----
    __syncthreads();
    __shared__ int lastFlag;
    if (tid == 0) {
        __threadfence();
        const unsigned t = atomicAdd(&ws->cnt, 1u);
        lastFlag = (t == gridDim.x - 1) ? 1 : 0;
    }
    __syncthreads();
    if (!lastFlag) return;
    __threadfence();

    __shared__ float epi[576];             // eS[8][64] + eN[8][8]
    __shared__ float eLse, eCe;
    for (int j = tid; j < 577; j += THREADS) {
        float a = 0.f;
        if (j < 512) {
            const int bb = j >> 6, ee = j & 63;
#pragma unroll
            for (int s8 = 0; s8 < NSLICE; ++s8) a += atomicAdd(&ws->S[s8][bb][ee], 0.f);
            epi[j] = a;
        } else if (j < 576) {
            const int q = j - 512, bb = q >> 3, k = q & 7;
#pragma unroll
            for (int s8 = 0; s8 < NSLICE; ++s8) a += atomicAdd(&ws->n[s8][bb][k], 0.f);
            epi[j] = a;
        } else {
#pragma unroll
            for (int s8 = 0; s8 < NSLICE; ++s8) a += atomicAdd(&ws->lse[s8], 0.f);
            eLse = a;
        }
    }
    __syncthreads();

    // ce = (sum lse - sum_b trace(S_b)) / (B*N)
    if (tid < 64) {
        const int bb = tid >> 3, kk = tid & 7;
        float tv = epi[bb * 64 + kk * 9];
        tv = wave_reduce(tv);
        if (tid == 0) eCe = (eLse - tv) / ((float)BATCH * (float)N);
    }
    __syncthreads();

    // j[b] = -sum_{i!=k} w[i,k]*log(0.5 + 0.5*(A[i,i]-A[i,k])); out = j + ce
    if (wv < BATCH) {
        const int i = lane >> 3, k = lane & 7;
        const int bb = wv;
        const float A    = epi[bb * 64 + lane]  / epi[512 + bb * 8 + k];
        const float diag = epi[bb * 64 + i * 9] / epi[512 + bb * 8 + i];
        float term = 0.f;
        if (i != k)
            term = w[lane] * (log2f(0.5f + 0.5f * (diag - A)) * LN2);
        term = wave_reduce(term);
        if (lane == 0) out[bb] = -term + eCe;
    }
}

extern "C" void kernel_launch(void* const* d_in, const int* in_sizes, int n_in,
                              void* d_out, int out_size, void* d_ws, size_t ws_size,
                              hipStream_t stream) {
    const float* pred = (const float*)d_in[0];
    const int*   tgt  = (const int*)d_in[1];
    const float* w    = (const float*)d_in[2];
    float* out = (float*)d_out;

    const int N = in_sizes[1] / BATCH;        // H*W = 262144
    WS* ws = (WS*)d_ws;

    hipMemsetAsync(ws, 0, sizeof(WS), stream);
    jce_fused<<<dim3(BATCH * 32), dim3(THREADS), 0, stream>>>(pred, tgt, w, out, ws, N);
}